// Round 1
// baseline (11998.250 us; speedup 1.0000x reference)
//
#include <hip/hip_runtime.h>

#define SEQ 512
#define NB  32
#define HD  512
#define NG  2048

typedef __attribute__((ext_vector_type(8))) short bf16x8;
typedef __attribute__((ext_vector_type(4))) float f32x4;

__device__ __forceinline__ unsigned short f2bf(float x) {
  union { float f; unsigned u; } v; v.f = x;
  unsigned r = v.u + 0x7fffu + ((v.u >> 16) & 1u);
  return (unsigned short)(r >> 16);
}
__device__ __forceinline__ float bf2f(unsigned short h) {
  union { float f; unsigned u; } v; v.u = ((unsigned)h) << 16;
  return v.f;
}
__device__ __forceinline__ float sigmoidf_(float x) {
  return 1.0f / (1.0f + __expf(-x));
}

// Monotonic-counter grid barrier. bar[0]=arrival count, bar[1]=generation.
__device__ __forceinline__ void grid_barrier(unsigned* bar, unsigned nwg, unsigned target) {
  __syncthreads();
  if (threadIdx.x == 0) {
    __threadfence();  // release: agent scope (wbl2 on gfx950)
    unsigned prev = __hip_atomic_fetch_add(&bar[0], 1u, __ATOMIC_ACQ_REL, __HIP_MEMORY_SCOPE_AGENT);
    if (prev + 1u == target * nwg) {
      __hip_atomic_store(&bar[1], target, __ATOMIC_RELEASE, __HIP_MEMORY_SCOPE_AGENT);
    } else {
      unsigned cur;
      do {
        __builtin_amdgcn_s_sleep(2);
        cur = __hip_atomic_load(&bar[1], __ATOMIC_RELAXED, __HIP_MEMORY_SCOPE_AGENT);
      } while (cur < target);
    }
    __threadfence();  // acquire: invalidate L1/L2 before re-reading h
  }
  __syncthreads();
}

// Generic 64x64-tile bf16 MFMA GEMM: C[M][Ncols] = A[M][K] @ B[Ncols][K]^T + bias
// AMODE 0: A = f32 x, row r -> (b = r&31, s = r>>5), row ptr x + (b*SEQ+s)*HD
// AMODE 1: A = bf16 contiguous rows of length 512
// AMODE 2: A = bf16 split rows (output projection, K=1024), C stored f32
template <int AMODE>
__global__ __launch_bounds__(256) void gemm_kernel(
    const float* __restrict__ Af32,
    const unsigned short* __restrict__ Abf,
    const float* __restrict__ Bw,
    const float* __restrict__ bias1,
    const float* __restrict__ bias2,
    unsigned short* __restrict__ Cbf,
    float* __restrict__ Cf32,
    int K, int Ncols)
{
  const int m0 = blockIdx.x * 64;
  const int n0 = blockIdx.y * 64;
  const int t = threadIdx.x;
  const int lane = t & 63;
  const int w = t >> 6;
  const int wm = w >> 1, wn = w & 1;

  __shared__ unsigned short As[64][72];
  __shared__ unsigned short Bs[64][72];

  f32x4 acc[2][2];
#pragma unroll
  for (int i = 0; i < 2; i++)
#pragma unroll
    for (int j = 0; j < 2; j++) acc[i][j] = (f32x4){0.f, 0.f, 0.f, 0.f};

  const int sr = t >> 2;
  const int sc = (t & 3) * 16;

  for (int k0 = 0; k0 < K; k0 += 64) {
    // ---- stage A tile ----
    {
      const int R = m0 + sr;
      const int kc = k0 + sc;
      if (AMODE == 0) {
        const int b = R & 31, s = R >> 5;
        const float* ap = Af32 + ((size_t)(b * SEQ + s)) * HD + kc;
#pragma unroll
        for (int i = 0; i < 16; i += 4) {
          float4 v = *(const float4*)(ap + i);
          As[sr][sc + i + 0] = f2bf(v.x);
          As[sr][sc + i + 1] = f2bf(v.y);
          As[sr][sc + i + 2] = f2bf(v.z);
          As[sr][sc + i + 3] = f2bf(v.w);
        }
      } else if (AMODE == 1) {
        const unsigned short* ap = Abf + (size_t)R * 512 + kc;
        *(bf16x8*)&As[sr][sc] = *(const bf16x8*)ap;
        *(bf16x8*)&As[sr][sc + 8] = *(const bf16x8*)(ap + 8);
      } else {
        const int b = R >> 9, s = R & 511;
        const unsigned short* ap;
        if (kc < 512) ap = Abf + ((size_t)(s * 64 + b)) * 512 + kc;
        else          ap = Abf + ((size_t)((511 - s) * 64 + 32 + b)) * 512 + (kc - 512);
        *(bf16x8*)&As[sr][sc] = *(const bf16x8*)ap;
        *(bf16x8*)&As[sr][sc + 8] = *(const bf16x8*)(ap + 8);
      }
      // ---- stage B tile (weights f32 [N][K]) ----
      const float* bp = Bw + (size_t)(n0 + sr) * K + k0 + sc;
#pragma unroll
      for (int i = 0; i < 16; i += 4) {
        float4 v = *(const float4*)(bp + i);
        Bs[sr][sc + i + 0] = f2bf(v.x);
        Bs[sr][sc + i + 1] = f2bf(v.y);
        Bs[sr][sc + i + 2] = f2bf(v.z);
        Bs[sr][sc + i + 3] = f2bf(v.w);
      }
    }
    __syncthreads();
#pragma unroll
    for (int kk = 0; kk < 64; kk += 32) {
      bf16x8 a[2], b[2];
#pragma unroll
      for (int mf = 0; mf < 2; mf++)
        a[mf] = *(const bf16x8*)&As[wm * 32 + mf * 16 + (lane & 15)][kk + (lane >> 4) * 8];
#pragma unroll
      for (int nf = 0; nf < 2; nf++)
        b[nf] = *(const bf16x8*)&Bs[wn * 32 + nf * 16 + (lane & 15)][kk + (lane >> 4) * 8];
#pragma unroll
      for (int mf = 0; mf < 2; mf++)
#pragma unroll
        for (int nf = 0; nf < 2; nf++)
          acc[mf][nf] = __builtin_amdgcn_mfma_f32_16x16x32_bf16(a[mf], b[nf], acc[mf][nf], 0, 0, 0);
    }
    __syncthreads();
  }

  // ---- epilogue ----
#pragma unroll
  for (int mf = 0; mf < 2; mf++) {
#pragma unroll
    for (int nf = 0; nf < 2; nf++) {
      const int col = n0 + wn * 32 + nf * 16 + (lane & 15);
      float bs = bias1[col] + (bias2 ? bias2[col] : 0.f);
#pragma unroll
      for (int r = 0; r < 4; r++) {
        const int row = m0 + wm * 32 + mf * 16 + (lane >> 4) * 4 + r;
        const float v = acc[mf][nf][r] + bs;
        if (AMODE == 2) Cf32[(size_t)row * Ncols + col] = v;
        else            Cbf[(size_t)row * Ncols + col] = f2bf(v);
      }
    }
  }
}

// Recurrence kernel: one layer, both directions batched as M=64 rows
// (rows 0..31 forward batches, 32..63 reverse batches).
// 32 WGs x 512 threads; WG g owns hidden units [16g, 16g+16) => gate cols
// {16g+u, 512+16g+u, 1024+16g+u, 1536+16g+u}. Whh slice lives in LDS (bf16,
// MFMA fragment order). One device-wide barrier per step.
__global__ __launch_bounds__(512) void rec_kernel(
    const unsigned short* __restrict__ Gin,  // mode 0: [s][32][2048]; mode 1: [t][64][2048]
    int ginMode,
    const float* __restrict__ Whh,   // [2048][512] f32 (layer slice)
    const float* __restrict__ h0,    // [32][512] f32 (layer slice)
    const float* __restrict__ c0,    // [32][512] f32 (layer slice)
    unsigned short* __restrict__ hinit,  // [64][512] bf16 scratch
    unsigned short* __restrict__ hout,   // [512][64][512] bf16
    float* __restrict__ hT,          // [32][2][512] f32 (layer slice)
    float* __restrict__ cT,          // [32][2][512] f32
    unsigned* __restrict__ bar)
{
  const int g = blockIdx.x;       // 0..31
  const int tid = threadIdx.x;    // 0..511
  const int lane = tid & 63;
  const int w = tid >> 6;         // 0..7
  const int chunk = w >> 1;       // gate chunk: 0=i,1=f,2=g,3=o
  const int mh = w & 1;           // row half (rows mh*32 .. mh*32+32)

  __shared__ unsigned short wlds[4][16][64][8];  // 64 KB, fragment order
  __shared__ float gates[4][64][17];             // ~17 KB, padded

  // ---- stage Whh slice into LDS (fragment order, bf16) ----
#pragma unroll
  for (int i = 0; i < 8; i++) {
    const int ks = mh * 8 + i;
    const int row = chunk * 512 + g * 16 + (lane & 15);
    const int col = ks * 32 + (lane >> 4) * 8;
    const float* wp = Whh + (size_t)row * 512 + col;
    float4 v0 = *(const float4*)(wp);
    float4 v1 = *(const float4*)(wp + 4);
    bf16x8 wv;
    wv[0] = (short)f2bf(v0.x); wv[1] = (short)f2bf(v0.y);
    wv[2] = (short)f2bf(v0.z); wv[3] = (short)f2bf(v0.w);
    wv[4] = (short)f2bf(v1.x); wv[5] = (short)f2bf(v1.y);
    wv[6] = (short)f2bf(v1.z); wv[7] = (short)f2bf(v1.w);
    *(bf16x8*)&wlds[chunk][ks][lane][0] = wv;
  }

  // ---- init h (global bf16) and c (registers) ----
  // thread handles (m, u0) and (m, u0+1):
  const int m = tid >> 3;
  const int u0 = (tid & 7) * 2;
  const int b = m & 31;
  const int dir = m >> 5;
  float c0r = c0[(size_t)b * 512 + g * 16 + u0];
  float c1r = c0[(size_t)b * 512 + g * 16 + u0 + 1];
  {
    const float h00 = h0[(size_t)b * 512 + g * 16 + u0];
    const float h01 = h0[(size_t)b * 512 + g * 16 + u0 + 1];
    const unsigned pack = (unsigned)f2bf(h00) | ((unsigned)f2bf(h01) << 16);
    *(unsigned*)&hinit[(size_t)m * 512 + g * 16 + u0] = pack;
  }
  grid_barrier(bar, 32u, 1u);

  for (int t = 0; t < SEQ; t++) {
    // ---- issue Gin loads early (consumed in pointwise) ----
    size_t grow;
    if (ginMode == 0) {
      const int tau = (m < 32) ? t : (SEQ - 1 - t);
      grow = (size_t)(tau * 32 + b);
    } else {
      grow = (size_t)(t * 64 + m);
    }
    const unsigned short* gp = Gin + grow * 2048 + g * 16 + u0;
    const unsigned gin_i = *(const unsigned*)(gp + 0 * 512);
    const unsigned gin_f = *(const unsigned*)(gp + 1 * 512);
    const unsigned gin_g = *(const unsigned*)(gp + 2 * 512);
    const unsigned gin_o = *(const unsigned*)(gp + 3 * 512);

    const unsigned short* hprev = (t == 0) ? hinit : (hout + (size_t)(t - 1) * 64 * 512);

    // ---- recurrent matmul: wave (chunk, mh) -> rows [mh*32, mh*32+32), 16 cols ----
    f32x4 acc[2];
    acc[0] = (f32x4){0.f, 0.f, 0.f, 0.f};
    acc[1] = (f32x4){0.f, 0.f, 0.f, 0.f};
#pragma unroll
    for (int ks = 0; ks < 16; ks++) {
      const bf16x8 bfrag = *(const bf16x8*)&wlds[chunk][ks][lane][0];
#pragma unroll
      for (int j = 0; j < 2; j++) {
        const int row = mh * 32 + j * 16 + (lane & 15);
        const unsigned short* apt = hprev + (size_t)row * 512 + ks * 32 + (lane >> 4) * 8;
        const bf16x8 afrag = *(const bf16x8*)apt;
        acc[j] = __builtin_amdgcn_mfma_f32_16x16x32_bf16(afrag, bfrag, acc[j], 0, 0, 0);
      }
    }
    // ---- write gates to LDS ----
#pragma unroll
    for (int j = 0; j < 2; j++)
#pragma unroll
      for (int r = 0; r < 4; r++)
        gates[chunk][mh * 32 + j * 16 + (lane >> 4) * 4 + r][lane & 15] = acc[j][r];
    __syncthreads();

    // ---- pointwise LSTM update ----
    {
      const float xi0 = gates[0][m][u0]     + bf2f((unsigned short)(gin_i & 0xffffu));
      const float xi1 = gates[0][m][u0 + 1] + bf2f((unsigned short)(gin_i >> 16));
      const float xf0 = gates[1][m][u0]     + bf2f((unsigned short)(gin_f & 0xffffu));
      const float xf1 = gates[1][m][u0 + 1] + bf2f((unsigned short)(gin_f >> 16));
      const float xg0 = gates[2][m][u0]     + bf2f((unsigned short)(gin_g & 0xffffu));
      const float xg1 = gates[2][m][u0 + 1] + bf2f((unsigned short)(gin_g >> 16));
      const float xo0 = gates[3][m][u0]     + bf2f((unsigned short)(gin_o & 0xffffu));
      const float xo1 = gates[3][m][u0 + 1] + bf2f((unsigned short)(gin_o >> 16));
      c0r = sigmoidf_(xf0) * c0r + sigmoidf_(xi0) * tanhf(xg0);
      c1r = sigmoidf_(xf1) * c1r + sigmoidf_(xi1) * tanhf(xg1);
      const float hv0 = sigmoidf_(xo0) * tanhf(c0r);
      const float hv1 = sigmoidf_(xo1) * tanhf(c1r);
      const unsigned pack = (unsigned)f2bf(hv0) | ((unsigned)f2bf(hv1) << 16);
      *(unsigned*)&hout[((size_t)t * 64 + m) * 512 + g * 16 + u0] = pack;
      if (t == SEQ - 1) {
        const size_t o = ((size_t)b * 2 + dir) * 512 + g * 16 + u0;
        hT[o] = hv0; hT[o + 1] = hv1;
        cT[o] = c0r; cT[o + 1] = c1r;
      }
    }
    if (t < SEQ - 1) grid_barrier(bar, 32u, (unsigned)(t + 2));
  }
}

// hid / cel projections: row r=(l*32+b), A row = concat(hT_f, hT_r) (1024 f32)
__global__ __launch_bounds__(256) void hidcel_kernel(
    const float* __restrict__ hTbuf, const float* __restrict__ cTbuf,
    const float* __restrict__ Whid, const float* __restrict__ bhid,
    const float* __restrict__ Wcell, const float* __restrict__ bcell,
    float* __restrict__ out)
{
  const int r = blockIdx.x;       // 0..63
  const int which = blockIdx.y;   // 0=hid, 1=cel
  const float* A = (which ? cTbuf : hTbuf) + (size_t)r * 1024;
  const float* W = which ? Wcell : Whid;
  const float* bias = which ? bcell : bhid;
  float* o = out + 8388608 + which * 32768 + (size_t)r * 512;
  __shared__ float arow[1024];
  for (int i = threadIdx.x; i < 1024; i += 256) arow[i] = A[i];
  __syncthreads();
  for (int n = threadIdx.x; n < 512; n += 256) {
    const float* wr = W + (size_t)n * 1024;
    float s = bias[n];
    for (int k = 0; k < 1024; k += 4) {
      float4 wv = *(const float4*)(wr + k);
      s += arow[k] * wv.x + arow[k + 1] * wv.y + arow[k + 2] * wv.z + arow[k + 3] * wv.w;
    }
    o[n] = s;
  }
}

extern "C" void kernel_launch(void* const* d_in, const int* in_sizes, int n_in,
                              void* d_out, int out_size, void* d_ws, size_t ws_size,
                              hipStream_t stream) {
  const float* x     = (const float*)d_in[0];
  const float* h0    = (const float*)d_in[1];
  const float* c0    = (const float*)d_in[2];
  const float* Wih   = (const float*)d_in[3];
  const float* Whh   = (const float*)d_in[4];
  const float* bih   = (const float*)d_in[5];
  const float* bhh   = (const float*)d_in[6];
  const float* Wout  = (const float*)d_in[7];
  const float* bout  = (const float*)d_in[8];
  const float* Whid  = (const float*)d_in[9];
  const float* bhid  = (const float*)d_in[10];
  const float* Wcell = (const float*)d_in[11];
  const float* bcell = (const float*)d_in[12];
  float* out = (float*)d_out;

  char* ws = (char*)d_ws;
  unsigned short* Gbuf  = (unsigned short*)ws;                         // up to 134217728 B (Gin0 uses half)
  unsigned short* h0buf = (unsigned short*)(ws + 134217728);           // 33554432 B
  unsigned short* h1buf = (unsigned short*)(ws + 134217728 + 33554432);// 33554432 B
  unsigned short* hinit = (unsigned short*)(ws + 134217728 + 2 * 33554432);      // 65536 B
  float* hTbuf = (float*)(ws + 134217728 + 2 * 33554432 + 65536);      // 262144 B
  float* cTbuf = hTbuf + 65536;                                        // 262144 B
  unsigned* bars = (unsigned*)((char*)cTbuf + 262144);                 // 16 B

  hipMemsetAsync(bars, 0, 16, stream);

  // 1. Gin0 = x @ Wih0^T + bih0 + bhh0   (layout [s][b][2048], bf16)
  gemm_kernel<0><<<dim3(256, 32), 256, 0, stream>>>(
      x, nullptr, Wih, bih, bhh, Gbuf, nullptr, 512, 2048);

  // 2. layer-0 recurrence (both dirs)
  rec_kernel<<<32, 512, 0, stream>>>(
      Gbuf, 0, Whh, h0, c0, hinit, h0buf, hTbuf, cTbuf, bars);

  // 3. Gin1 = h0buf @ Wih1^T + bih1 + bhh1  (layout [t][m][2048], bf16)
  gemm_kernel<1><<<dim3(512, 32), 256, 0, stream>>>(
      nullptr, h0buf, Wih + 2048 * 512, bih + 2048, bhh + 2048, Gbuf, nullptr, 512, 2048);

  // 4. layer-1 recurrence
  rec_kernel<<<32, 512, 0, stream>>>(
      Gbuf, 1, Whh + 2048 * 512, h0 + 32 * 512, c0 + 32 * 512, hinit, h1buf,
      hTbuf + 32768, cTbuf + 32768, bars + 2);

  // 5. output projection -> d_out[0 .. 8388608)
  gemm_kernel<2><<<dim3(256, 8), 256, 0, stream>>>(
      nullptr, h1buf, Wout, bout, nullptr, nullptr, out, 1024, 512);

  // 6. hid / cel projections -> d_out[8388608 ..)
  hidcel_kernel<<<dim3(64, 2), 256, 0, stream>>>(
      hTbuf, cTbuf, Whid, bhid, Wcell, bcell, out);
}

// Round 2
// 6352.977 us; speedup vs baseline: 1.8886x; 1.8886x over previous
//
#include <hip/hip_runtime.h>

#define SEQ 512
#define HD  512
#define NGHD (2048 * 512)

typedef __attribute__((ext_vector_type(8))) short bf16x8;
typedef __attribute__((ext_vector_type(4))) float f32x4;

__device__ __forceinline__ unsigned short f2bf(float x) {
  union { float f; unsigned u; } v; v.f = x;
  unsigned r = v.u + 0x7fffu + ((v.u >> 16) & 1u);
  return (unsigned short)(r >> 16);
}
__device__ __forceinline__ float bf2f(unsigned short h) {
  union { float f; unsigned u; } v; v.u = ((unsigned)h) << 16;
  return v.f;
}
__device__ __forceinline__ float fsig(float x) {
  return __builtin_amdgcn_rcpf(1.0f + __expf(-x));
}
__device__ __forceinline__ float ftanh(float x) {
  return 1.0f - 2.0f * __builtin_amdgcn_rcpf(1.0f + __expf(2.0f * x));
}
__device__ __forceinline__ bf16x8 pack8(const float* wp) {
  float4 v0 = *(const float4*)wp;
  float4 v1 = *(const float4*)(wp + 4);
  bf16x8 wv;
  wv[0] = (short)f2bf(v0.x); wv[1] = (short)f2bf(v0.y);
  wv[2] = (short)f2bf(v0.z); wv[3] = (short)f2bf(v0.w);
  wv[4] = (short)f2bf(v1.x); wv[5] = (short)f2bf(v1.y);
  wv[6] = (short)f2bf(v1.z); wv[7] = (short)f2bf(v1.w);
  return wv;
}

// Coherent (cross-XCD) access helpers: sc0 sc1 = read/write at the device
// coherence point (bypass L1/L2). No wbl2/inv cache maintenance anywhere.
#define AFL(dst, VOFF, SB, IMM) \
  asm volatile("global_load_dwordx4 %0, %1, %2 offset:" IMM " sc0 sc1" \
               : "=v"(dst) : "v"(VOFF), "s"(SB))
#define GLD(dst, VOFF, SB, IMM) \
  asm volatile("global_load_dword %0, %1, %2 offset:" IMM \
               : "=v"(dst) : "v"(VOFF), "s"(SB))
#define CST(VOFF, VAL, SB) \
  asm volatile("global_store_dword %0, %1, %2 sc0 sc1" \
               :: "v"(VOFF), "v"(VAL), "s"(SB))
#define VDRAIN asm volatile("s_waitcnt vmcnt(0)" ::: "memory")

// Relaxed monotonic grid barrier: data visibility is guaranteed by the
// sc0/sc1 write-through stores (drained via vmcnt(0) before arrival) and
// sc0/sc1 bypass loads after release — no fences needed.
__device__ __forceinline__ void gbar(unsigned* bar, unsigned gen) {
  __syncthreads();
  if (threadIdx.x == 0) {
    const unsigned prev = __hip_atomic_fetch_add(&bar[0], 1u, __ATOMIC_RELAXED,
                                                 __HIP_MEMORY_SCOPE_AGENT);
    if (prev + 1u == gen * 64u) {
      __hip_atomic_store(&bar[1], gen, __ATOMIC_RELAXED, __HIP_MEMORY_SCOPE_AGENT);
    } else {
      while (__hip_atomic_load(&bar[1], __ATOMIC_RELAXED, __HIP_MEMORY_SCOPE_AGENT) < gen) {
        __builtin_amdgcn_s_sleep(1);
      }
    }
  }
  __syncthreads();
}

// ---------------------------------------------------------------------------
// Generic 64x64-tile bf16 MFMA GEMM: C[M][N] = A[M][K] @ B[N][K]^T + bias
// AMODE 0: A = f32 x, row r -> (b=r&31, s=r>>5); C bf16 [s][b][2048]
// AMODE 2: A = bf16 h1buf split rows (K=1024); C f32
// ---------------------------------------------------------------------------
template <int AMODE>
__global__ __launch_bounds__(256) void gemm_kernel(
    const float* __restrict__ Af32,
    const unsigned short* __restrict__ Abf,
    const float* __restrict__ Bw,
    const float* __restrict__ bias1,
    const float* __restrict__ bias2,
    unsigned short* __restrict__ Cbf,
    float* __restrict__ Cf32,
    int K, int Ncols)
{
  const int m0 = blockIdx.x * 64;
  const int n0 = blockIdx.y * 64;
  const int t = threadIdx.x;
  const int lane = t & 63;
  const int w = t >> 6;
  const int wm = w >> 1, wn = w & 1;

  __shared__ unsigned short As[64][72];
  __shared__ unsigned short Bs[64][72];

  f32x4 acc[2][2];
#pragma unroll
  for (int i = 0; i < 2; i++)
#pragma unroll
    for (int j = 0; j < 2; j++) acc[i][j] = (f32x4){0.f, 0.f, 0.f, 0.f};

  const int sr = t >> 2;
  const int sc = (t & 3) * 16;

  for (int k0 = 0; k0 < K; k0 += 64) {
    const int R = m0 + sr;
    const int kc = k0 + sc;
    if (AMODE == 0) {
      const int b = R & 31, s = R >> 5;
      const float* ap = Af32 + ((size_t)(b * SEQ + s)) * HD + kc;
#pragma unroll
      for (int i = 0; i < 16; i += 8)
        *(bf16x8*)&As[sr][sc + i] = pack8(ap + i);
    } else {
      const int b = R >> 9, s = R & 511;
      const unsigned short* ap;
      if (kc < 512) ap = Abf + ((size_t)(s * 64 + b)) * 512 + kc;
      else          ap = Abf + ((size_t)((511 - s) * 64 + 32 + b)) * 512 + (kc - 512);
      *(bf16x8*)&As[sr][sc] = *(const bf16x8*)ap;
      *(bf16x8*)&As[sr][sc + 8] = *(const bf16x8*)(ap + 8);
    }
    const float* bp = Bw + (size_t)(n0 + sr) * K + k0 + sc;
#pragma unroll
    for (int i = 0; i < 16; i += 8)
      *(bf16x8*)&Bs[sr][sc + i] = pack8(bp + i);
    __syncthreads();
#pragma unroll
    for (int kk = 0; kk < 64; kk += 32) {
      bf16x8 a[2], b[2];
#pragma unroll
      for (int mf = 0; mf < 2; mf++)
        a[mf] = *(const bf16x8*)&As[wm * 32 + mf * 16 + (lane & 15)][kk + (lane >> 4) * 8];
#pragma unroll
      for (int nf = 0; nf < 2; nf++)
        b[nf] = *(const bf16x8*)&Bs[wn * 32 + nf * 16 + (lane & 15)][kk + (lane >> 4) * 8];
#pragma unroll
      for (int mf = 0; mf < 2; mf++)
#pragma unroll
        for (int nf = 0; nf < 2; nf++)
          acc[mf][nf] = __builtin_amdgcn_mfma_f32_16x16x32_bf16(a[mf], b[nf], acc[mf][nf], 0, 0, 0);
    }
    __syncthreads();
  }

#pragma unroll
  for (int mf = 0; mf < 2; mf++) {
#pragma unroll
    for (int nf = 0; nf < 2; nf++) {
      const int col = n0 + wn * 32 + nf * 16 + (lane & 15);
      float bs = bias1[col] + (bias2 ? bias2[col] : 0.f);
#pragma unroll
      for (int r = 0; r < 4; r++) {
        const int row = m0 + wm * 32 + mf * 16 + (lane >> 4) * 4 + r;
        const float v = acc[mf][nf][r] + bs;
        if (AMODE == 2) Cf32[(size_t)row * Ncols + col] = v;
        else            Cbf[(size_t)row * Ncols + col] = f2bf(v);
      }
    }
  }
}

// ---------------------------------------------------------------------------
// Fused 2-layer bidirectional recurrence, pipelined across layers.
// 64 WGs x 512 threads, 1 WG/CU (LDS 145 KB). WGs 0..31 = layer 0,
// WGs 32..63 = layer 1 (lags one round). Round tau: L0 computes t=tau,
// L1 computes t=tau-1 from h0buf[tau-1] (+ its Wih1 folded into the MFMA).
// M=64 rows = {fwd batches 0..31, rev batches 0..31}. WG g owns 16 hidden
// units -> 64 gate columns; weights LDS-resident in MFMA fragment order.
// Waves: (rq = row quarter 0..3) x (cg = chunk pair 0..1).
// ---------------------------------------------------------------------------
__global__ __launch_bounds__(512, 2) void rec2_kernel(
    const unsigned short* __restrict__ Gin,   // [512][32][2048] bf16 (L0 pre-gates)
    const float* __restrict__ Wih,            // [2][2048][512]
    const float* __restrict__ Whh,            // [2][2048][512]
    const float* __restrict__ bih,            // [2][2048]
    const float* __restrict__ bhh,            // [2][2048]
    const float* __restrict__ h0,             // [2][32][512]
    const float* __restrict__ c0,             // [2][32][512]
    unsigned short* __restrict__ hIn0,        // [64][512] bf16
    unsigned short* __restrict__ hIn1,        // [64][512] bf16
    unsigned short* __restrict__ h0buf,       // [512][64][512] bf16
    unsigned short* __restrict__ h1buf,       // [512][64][512] bf16
    float* __restrict__ hT,                   // [2][32][2][512] f32
    float* __restrict__ cT,                   // [2][32][2][512] f32
    unsigned* __restrict__ bar)
{
  const int wg = blockIdx.x;
  const bool isL1 = wg >= 32;
  const int g = wg & 31;
  const int tid = threadIdx.x;
  const int lane = tid & 63;
  const int w = tid >> 6;
  const int rq = w >> 1;          // row quarter 0..3
  const int cg2 = (w & 1) * 2;    // first chunk of this wave's chunk pair

  __shared__ unsigned short wlds[4][32][64][8];  // 128 KB weight fragments
  __shared__ float gates[4][64][17];             // 17 KB padded

  // ---- stage weights into LDS (MFMA B-fragment order, bf16) ----
  if (isL1) {
    const float* W0 = Wih + NGHD;   // ks 0..15  : input projection (h0_cur)
    const float* W1 = Whh + NGHD;   // ks 16..31 : recurrent (h1_prev)
#pragma unroll
    for (int i = 0; i < 16; i++) {
      const int p = i * 8 + w;
      const int c = p >> 5, ks = p & 31;
      const int row = c * 512 + g * 16 + (lane & 15);
      const float* wp = (ks < 16)
          ? (W0 + (size_t)row * 512 + ks * 32 + (lane >> 4) * 8)
          : (W1 + (size_t)row * 512 + (ks - 16) * 32 + (lane >> 4) * 8);
      *(bf16x8*)&wlds[c][ks][lane][0] = pack8(wp);
    }
  } else {
#pragma unroll
    for (int i = 0; i < 8; i++) {
      const int p = i * 8 + w;
      const int c = p >> 4, ks = p & 15;
      const float* wp = Whh + (size_t)(c * 512 + g * 16 + (lane & 15)) * 512
                        + ks * 32 + (lane >> 4) * 8;
      *(bf16x8*)&wlds[c][ks][lane][0] = pack8(wp);
    }
  }

  // ---- per-thread state ----
  const int m = tid >> 3;          // row 0..63
  const int u0 = (tid & 7) * 2;    // unit pair within g-slice
  const int b = m & 31;
  const int dir = m >> 5;
  const int l = isL1 ? 1 : 0;

  float cr0 = c0[(size_t)l * 16384 + b * 512 + g * 16 + u0];
  float cr1 = c0[(size_t)l * 16384 + b * 512 + g * 16 + u0 + 1];
  float bia[4][2] = {{0.f,0.f},{0.f,0.f},{0.f,0.f},{0.f,0.f}};
  if (isL1) {
#pragma unroll
    for (int c = 0; c < 4; c++) {
      const int o = 2048 + c * 512 + g * 16 + u0;
      bia[c][0] = bih[o] + bhh[o];
      bia[c][1] = bih[o + 1] + bhh[o + 1];
    }
  }

  // invariant per-lane byte offsets
  const unsigned aoff = (unsigned)(((rq * 16 + (lane & 15)) * 512 + (lane >> 4) * 8) * 2);
  const unsigned goff = (unsigned)((b * 2048 + g * 16 + u0) * 2);
  const unsigned soff = (unsigned)((m * 512 + g * 16 + u0) * 2);
  const int grow_ = rq * 16 + (lane >> 4) * 4;
  const int gcol_ = lane & 15;

  // ---- publish initial h ----
  {
    const float h00 = h0[(size_t)l * 16384 + b * 512 + g * 16 + u0];
    const float h01 = h0[(size_t)l * 16384 + b * 512 + g * 16 + u0 + 1];
    const unsigned pack = (unsigned)f2bf(h00) | ((unsigned)f2bf(h01) << 16);
    unsigned short* hIn = isL1 ? hIn1 : hIn0;
    CST(soff, pack, hIn);
  }
  VDRAIN;
  gbar(bar, 1u);

  for (int tau = 0; tau <= 512; ++tau) {
    const bool act = isL1 ? (tau >= 1) : (tau <= 511);
    if (act) {
      const int t = isL1 ? (tau - 1) : tau;
      unsigned gi = 0, gf = 0, gg = 0, go = 0;
      bf16x8 af[32];
      f32x4 a0 = (f32x4){0.f, 0.f, 0.f, 0.f};
      f32x4 a1 = (f32x4){0.f, 0.f, 0.f, 0.f};

      if (!isL1) {
        const unsigned tsel = (unsigned)__builtin_amdgcn_readfirstlane((m < 32) ? t : (SEQ - 1) - t);
        const unsigned short* gb = Gin + (size_t)tsel * 65536;
        GLD(gi, goff, gb, "0");
        GLD(gf, goff, gb, "1024");
        GLD(gg, goff, gb, "2048");
        GLD(go, goff, gb, "3072");
        const unsigned short* s0 = (tau == 0) ? hIn0 : (h0buf + (size_t)(tau - 1) * 32768);
        AFL(af[0],  aoff, s0, "0");   AFL(af[1],  aoff, s0, "64");
        AFL(af[2],  aoff, s0, "128"); AFL(af[3],  aoff, s0, "192");
        AFL(af[4],  aoff, s0, "256"); AFL(af[5],  aoff, s0, "320");
        AFL(af[6],  aoff, s0, "384"); AFL(af[7],  aoff, s0, "448");
        AFL(af[8],  aoff, s0, "512"); AFL(af[9],  aoff, s0, "576");
        AFL(af[10], aoff, s0, "640"); AFL(af[11], aoff, s0, "704");
        AFL(af[12], aoff, s0, "768"); AFL(af[13], aoff, s0, "832");
        AFL(af[14], aoff, s0, "896"); AFL(af[15], aoff, s0, "960");
        bf16x8 b0p = *(const bf16x8*)&wlds[cg2][0][lane][0];
        bf16x8 b1p = *(const bf16x8*)&wlds[cg2 + 1][0][lane][0];
        VDRAIN;
        __builtin_amdgcn_sched_barrier(0);
        a0 = __builtin_amdgcn_mfma_f32_16x16x32_bf16(af[0], b0p, a0, 0, 0, 0);
        a1 = __builtin_amdgcn_mfma_f32_16x16x32_bf16(af[0], b1p, a1, 0, 0, 0);
#pragma unroll
        for (int ks = 1; ks < 16; ks++) {
          bf16x8 b0 = *(const bf16x8*)&wlds[cg2][ks][lane][0];
          bf16x8 b1 = *(const bf16x8*)&wlds[cg2 + 1][ks][lane][0];
          a0 = __builtin_amdgcn_mfma_f32_16x16x32_bf16(af[ks], b0, a0, 0, 0, 0);
          a1 = __builtin_amdgcn_mfma_f32_16x16x32_bf16(af[ks], b1, a1, 0, 0, 0);
        }
      } else {
        const unsigned short* s0 = h0buf + (size_t)(tau - 1) * 32768;
        const unsigned short* s1 = (tau == 1) ? hIn1 : (h1buf + (size_t)(tau - 2) * 32768);
        AFL(af[0],  aoff, s0, "0");   AFL(af[1],  aoff, s0, "64");
        AFL(af[2],  aoff, s0, "128"); AFL(af[3],  aoff, s0, "192");
        AFL(af[4],  aoff, s0, "256"); AFL(af[5],  aoff, s0, "320");
        AFL(af[6],  aoff, s0, "384"); AFL(af[7],  aoff, s0, "448");
        AFL(af[8],  aoff, s0, "512"); AFL(af[9],  aoff, s0, "576");
        AFL(af[10], aoff, s0, "640"); AFL(af[11], aoff, s0, "704");
        AFL(af[12], aoff, s0, "768"); AFL(af[13], aoff, s0, "832");
        AFL(af[14], aoff, s0, "896"); AFL(af[15], aoff, s0, "960");
        AFL(af[16], aoff, s1, "0");   AFL(af[17], aoff, s1, "64");
        AFL(af[18], aoff, s1, "128"); AFL(af[19], aoff, s1, "192");
        AFL(af[20], aoff, s1, "256"); AFL(af[21], aoff, s1, "320");
        AFL(af[22], aoff, s1, "384"); AFL(af[23], aoff, s1, "448");
        AFL(af[24], aoff, s1, "512"); AFL(af[25], aoff, s1, "576");
        AFL(af[26], aoff, s1, "640"); AFL(af[27], aoff, s1, "704");
        AFL(af[28], aoff, s1, "768"); AFL(af[29], aoff, s1, "832");
        AFL(af[30], aoff, s1, "896"); AFL(af[31], aoff, s1, "960");
        bf16x8 b0p = *(const bf16x8*)&wlds[cg2][0][lane][0];
        bf16x8 b1p = *(const bf16x8*)&wlds[cg2 + 1][0][lane][0];
        VDRAIN;
        __builtin_amdgcn_sched_barrier(0);
        a0 = __builtin_amdgcn_mfma_f32_16x16x32_bf16(af[0], b0p, a0, 0, 0, 0);
        a1 = __builtin_amdgcn_mfma_f32_16x16x32_bf16(af[0], b1p, a1, 0, 0, 0);
#pragma unroll
        for (int ks = 1; ks < 32; ks++) {
          bf16x8 b0 = *(const bf16x8*)&wlds[cg2][ks][lane][0];
          bf16x8 b1 = *(const bf16x8*)&wlds[cg2 + 1][ks][lane][0];
          a0 = __builtin_amdgcn_mfma_f32_16x16x32_bf16(af[ks], b0, a0, 0, 0, 0);
          a1 = __builtin_amdgcn_mfma_f32_16x16x32_bf16(af[ks], b1, a1, 0, 0, 0);
        }
      }

      // ---- gate pre-activations -> LDS ----
#pragma unroll
      for (int r = 0; r < 4; r++) {
        gates[cg2][grow_ + r][gcol_]     = a0[r];
        gates[cg2 + 1][grow_ + r][gcol_] = a1[r];
      }
      __syncthreads();

      // ---- pointwise LSTM update ----
      float ad00, ad01, ad10, ad11, ad20, ad21, ad30, ad31;
      if (isL1) {
        ad00 = bia[0][0]; ad01 = bia[0][1];
        ad10 = bia[1][0]; ad11 = bia[1][1];
        ad20 = bia[2][0]; ad21 = bia[2][1];
        ad30 = bia[3][0]; ad31 = bia[3][1];
      } else {
        ad00 = bf2f((unsigned short)(gi & 0xffffu)); ad01 = bf2f((unsigned short)(gi >> 16));
        ad10 = bf2f((unsigned short)(gf & 0xffffu)); ad11 = bf2f((unsigned short)(gf >> 16));
        ad20 = bf2f((unsigned short)(gg & 0xffffu)); ad21 = bf2f((unsigned short)(gg >> 16));
        ad30 = bf2f((unsigned short)(go & 0xffffu)); ad31 = bf2f((unsigned short)(go >> 16));
      }
      const float xi0 = gates[0][m][u0]     + ad00;
      const float xi1 = gates[0][m][u0 + 1] + ad01;
      const float xf0 = gates[1][m][u0]     + ad10;
      const float xf1 = gates[1][m][u0 + 1] + ad11;
      const float xg0 = gates[2][m][u0]     + ad20;
      const float xg1 = gates[2][m][u0 + 1] + ad21;
      const float xo0 = gates[3][m][u0]     + ad30;
      const float xo1 = gates[3][m][u0 + 1] + ad31;
      cr0 = fsig(xf0) * cr0 + fsig(xi0) * ftanh(xg0);
      cr1 = fsig(xf1) * cr1 + fsig(xi1) * ftanh(xg1);
      const float hv0 = fsig(xo0) * ftanh(cr0);
      const float hv1 = fsig(xo1) * ftanh(cr1);
      const unsigned pack = (unsigned)f2bf(hv0) | ((unsigned)f2bf(hv1) << 16);
      unsigned short* hd = (isL1 ? h1buf : h0buf) + (size_t)t * 32768;
      CST(soff, pack, hd);
      if (t == SEQ - 1) {
        const size_t o = (size_t)l * 32768 + ((size_t)b * 2 + dir) * 512 + g * 16 + u0;
        hT[o] = hv0; hT[o + 1] = hv1;
        cT[o] = cr0; cT[o + 1] = cr1;
      }
      VDRAIN;
    }
    if (tau < 512) gbar(bar, (unsigned)(tau + 2));
  }
}

// hid / cel projections: row r = l*32+b, A row = concat over dir (1024 f32)
__global__ __launch_bounds__(256) void hidcel_kernel(
    const float* __restrict__ hTbuf, const float* __restrict__ cTbuf,
    const float* __restrict__ Whid, const float* __restrict__ bhid,
    const float* __restrict__ Wcell, const float* __restrict__ bcell,
    float* __restrict__ out)
{
  const int r = blockIdx.x;       // 0..63
  const int which = blockIdx.y;   // 0=hid, 1=cel
  const float* A = (which ? cTbuf : hTbuf) + (size_t)r * 1024;
  const float* W = which ? Wcell : Whid;
  const float* bias = which ? bcell : bhid;
  float* o = out + 8388608 + which * 32768 + (size_t)r * 512;
  __shared__ float arow[1024];
  for (int i = threadIdx.x; i < 1024; i += 256) arow[i] = A[i];
  __syncthreads();
  for (int n = threadIdx.x; n < 512; n += 256) {
    const float* wr = W + (size_t)n * 1024;
    float s = bias[n];
    for (int k = 0; k < 1024; k += 4) {
      float4 wv = *(const float4*)(wr + k);
      s += arow[k] * wv.x + arow[k + 1] * wv.y + arow[k + 2] * wv.z + arow[k + 3] * wv.w;
    }
    o[n] = s;
  }
}

extern "C" void kernel_launch(void* const* d_in, const int* in_sizes, int n_in,
                              void* d_out, int out_size, void* d_ws, size_t ws_size,
                              hipStream_t stream) {
  const float* x     = (const float*)d_in[0];
  const float* h0    = (const float*)d_in[1];
  const float* c0    = (const float*)d_in[2];
  const float* Wih   = (const float*)d_in[3];
  const float* Whh   = (const float*)d_in[4];
  const float* bih   = (const float*)d_in[5];
  const float* bhh   = (const float*)d_in[6];
  const float* Wout  = (const float*)d_in[7];
  const float* bout  = (const float*)d_in[8];
  const float* Whid  = (const float*)d_in[9];
  const float* bhid  = (const float*)d_in[10];
  const float* Wcell = (const float*)d_in[11];
  const float* bcell = (const float*)d_in[12];
  float* out = (float*)d_out;

  char* ws = (char*)d_ws;
  unsigned short* Gbuf  = (unsigned short*)(ws);                  // 64 MB [512][32][2048]
  unsigned short* h0buf = (unsigned short*)(ws + 67108864);       // 32 MB [512][64][512]
  unsigned short* h1buf = (unsigned short*)(ws + 100663296);      // 32 MB
  unsigned short* hIn0  = (unsigned short*)(ws + 134217728);      // 64 KB
  unsigned short* hIn1  = (unsigned short*)(ws + 134283264);      // 64 KB
  float* hTbuf = (float*)(ws + 134348800);                        // 256 KB [2][32][2][512]
  float* cTbuf = (float*)(ws + 134610944);                        // 256 KB
  unsigned* bars = (unsigned*)(ws + 134873088);                   // 16 B

  hipMemsetAsync(bars, 0, 16, stream);

  // 1. Gin0 = x @ Wih0^T + bih0 + bhh0   ([s][b][2048] bf16)
  gemm_kernel<0><<<dim3(256, 32), 256, 0, stream>>>(
      x, nullptr, Wih, bih, bhh, Gbuf, nullptr, 512, 2048);

  // 2. fused 2-layer bidirectional recurrence (layer-pipelined, 513 rounds)
  rec2_kernel<<<64, 512, 0, stream>>>(
      Gbuf, Wih, Whh, bih, bhh, h0, c0, hIn0, hIn1, h0buf, h1buf,
      hTbuf, cTbuf, bars);

  // 3. output projection -> d_out[0 .. 8388608)
  gemm_kernel<2><<<dim3(256, 8), 256, 0, stream>>>(
      nullptr, h1buf, Wout, bout, nullptr, nullptr, out, 1024, 512);

  // 4. hid / cel projections -> d_out[8388608 ..)
  hidcel_kernel<<<dim3(64, 2), 256, 0, stream>>>(
      hTbuf, cTbuf, Whid, bhid, Wcell, bcell, out);
}